// Round 1
// baseline (3326.623 us; speedup 1.0000x reference)
//
#include <hip/hip_runtime.h>
#include <hip/hip_bf16.h>

#define N_NODES 100000
#define N_EDGES 1000000
#define DIM 64
#define N_GRAPHS 256
#define OUT_DIM 10
#define BN_EPS 1e-5f

// ---------------------------------------------------------------------------
// Scatter-add: agg[dst] += x[src] for each edge. 16 threads per edge, each
// handling one float4 (4 atomic f32 adds). x-load is coalesced 256B per edge.
// ---------------------------------------------------------------------------
__global__ __launch_bounds__(256) void scatter_kernel(
    const float* __restrict__ x, const int* __restrict__ ei,
    float* __restrict__ agg)
{
    int t = blockIdx.x * 256 + threadIdx.x;
    if (t >= N_EDGES * 16) return;
    int e = t >> 4;
    int q = t & 15;
    int src = ei[e];
    int dst = ei[N_EDGES + e];
    float4 v = ((const float4*)x)[src * 16 + q];
    float* a = agg + dst * 64 + q * 4;
    unsafeAtomicAdd(a + 0, v.x);
    unsafeAtomicAdd(a + 1, v.y);
    unsafeAtomicAdd(a + 2, v.z);
    unsafeAtomicAdd(a + 3, v.w);
}

// ---------------------------------------------------------------------------
// Fused GIN MLP: h = (1+eps)*x + agg ; h1 = relu(h@w1+b1) ; h2 = relu(h1@w2+b2)
// Writes h2 in-place over agg, accumulates BN sum/sumsq per dim.
// One wave per node; lane = output dim. W held in VGPRs (w[:,lane] per lane),
// activation broadcast via v_readlane -> pure-VALU inner loop (no LDS pipe).
// ---------------------------------------------------------------------------
__global__ __launch_bounds__(256) void mlp_kernel(
    const float* __restrict__ x, float* __restrict__ h2buf,
    const float* __restrict__ w1, const float* __restrict__ b1,
    const float* __restrict__ w2, const float* __restrict__ b2,
    const float* __restrict__ eps_all, int layer,
    float* __restrict__ sums)
{
    const int lane = threadIdx.x & 63;
    const int wave = blockIdx.x * 4 + (threadIdx.x >> 6);
    const int nwaves = gridDim.x * 4;

    float w1r[64], w2r[64];
#pragma unroll
    for (int k = 0; k < 64; ++k) w1r[k] = w1[k * 64 + lane];  // coalesced
#pragma unroll
    for (int k = 0; k < 64; ++k) w2r[k] = w2[k * 64 + lane];
    const float b1v = b1[lane];
    const float b2v = b2[lane];
    const float epsv = 1.0f + eps_all[layer];

    float lsum = 0.0f, lsq = 0.0f;

    for (int n = wave; n < N_NODES; n += nwaves) {
        float xv = x[n * 64 + lane];
        float av = h2buf[n * 64 + lane];
        float h = fmaf(epsv, xv, av);

        float acc = b1v;
#pragma unroll
        for (int k = 0; k < 64; ++k) {
            float hk = __int_as_float(
                __builtin_amdgcn_readlane(__float_as_int(h), k));
            acc = fmaf(hk, w1r[k], acc);
        }
        float h1 = fmaxf(acc, 0.0f);

        float acc2 = b2v;
#pragma unroll
        for (int k = 0; k < 64; ++k) {
            float hk = __int_as_float(
                __builtin_amdgcn_readlane(__float_as_int(h1), k));
            acc2 = fmaf(hk, w2r[k], acc2);
        }
        float v = fmaxf(acc2, 0.0f);

        h2buf[n * 64 + lane] = v;
        lsum += v;
        lsq = fmaf(v, v, lsq);
    }
    unsafeAtomicAdd(&sums[lane], lsum);
    unsafeAtomicAdd(&sums[64 + lane], lsq);
}

// ---------------------------------------------------------------------------
// BatchNorm (training-mode batch stats, biased var) + ReLU, elementwise.
// ---------------------------------------------------------------------------
__global__ __launch_bounds__(256) void bn_kernel(
    const float4* __restrict__ h2, const float* __restrict__ sums,
    const float* __restrict__ gamma, const float* __restrict__ beta,
    float4* __restrict__ xo)
{
    int t = blockIdx.x * 256 + threadIdx.x;
    if (t >= N_NODES * 16) return;
    int q = t & 15;
    int d = q * 4;
    const float inv_n = 1.0f / (float)N_NODES;
    float4 v = h2[t];
    float4 o;
    float* vp = (float*)&v;
    float* op = (float*)&o;
#pragma unroll
    for (int j = 0; j < 4; ++j) {
        int dd = d + j;
        float mean = sums[dd] * inv_n;
        float m2 = sums[64 + dd] * inv_n;
        float var = m2 - mean * mean;
        float scale = gamma[dd] * rsqrtf(var + BN_EPS);
        float shift = fmaf(-mean, scale, beta[dd]);
        op[j] = fmaxf(fmaf(vp[j], scale, shift), 0.0f);
    }
    xo[t] = o;
}

// ---------------------------------------------------------------------------
// Global mean pool (accumulate sums + counts with atomics; batch is sorted
// but we rely on address spread across 256*64 targets).
// ---------------------------------------------------------------------------
__global__ __launch_bounds__(256) void pool_kernel(
    const float4* __restrict__ x, const int* __restrict__ batch,
    float* __restrict__ pooled, float* __restrict__ counts)
{
    int t = blockIdx.x * 256 + threadIdx.x;
    if (t >= N_NODES * 16) return;
    int n = t >> 4;
    int q = t & 15;
    int g = batch[n];
    float4 v = x[t];
    float* p = pooled + g * 64 + q * 4;
    unsafeAtomicAdd(p + 0, v.x);
    unsafeAtomicAdd(p + 1, v.y);
    unsafeAtomicAdd(p + 2, v.z);
    unsafeAtomicAdd(p + 3, v.w);
    if (q == 0) unsafeAtomicAdd(&counts[g], 1.0f);
}

// ---------------------------------------------------------------------------
// Final linear: out[g][o] = (sum_d pooled[g][d]*lin_w[d][o]) / max(cnt,1) + b[o]
// ---------------------------------------------------------------------------
__global__ __launch_bounds__(256) void final_kernel(
    const float* __restrict__ pooled, const float* __restrict__ counts,
    const float* __restrict__ lin_w, const float* __restrict__ lin_b,
    float* __restrict__ out)
{
    int t = blockIdx.x * 256 + threadIdx.x;
    if (t >= N_GRAPHS * OUT_DIM) return;
    int g = t / OUT_DIM;
    int o = t - g * OUT_DIM;
    float acc = 0.0f;
#pragma unroll 8
    for (int d = 0; d < 64; ++d)
        acc = fmaf(pooled[g * 64 + d], lin_w[d * OUT_DIM + o], acc);
    float c = fmaxf(counts[g], 1.0f);
    out[t] = acc / c + lin_b[o];
}

extern "C" void kernel_launch(void* const* d_in, const int* in_sizes, int n_in,
                              void* d_out, int out_size, void* d_ws, size_t ws_size,
                              hipStream_t stream)
{
    const float* x0    = (const float*)d_in[0];
    const int*   ei    = (const int*)d_in[1];
    const int*   batch = (const int*)d_in[2];
    const float* w1    = (const float*)d_in[3];
    const float* b1    = (const float*)d_in[4];
    const float* w2    = (const float*)d_in[5];
    const float* b2    = (const float*)d_in[6];
    const float* gamma = (const float*)d_in[7];
    const float* beta  = (const float*)d_in[8];
    const float* eps_g = (const float*)d_in[9];
    const float* lin_w = (const float*)d_in[10];
    const float* lin_b = (const float*)d_in[11];
    float* out = (float*)d_out;

    float* ws   = (float*)d_ws;
    float* A    = ws;                       // agg -> h2 (in place), 6.4M floats
    float* X    = ws + (size_t)N_NODES * 64;        // layer output, 6.4M floats
    float* SUMS = ws + (size_t)2 * N_NODES * 64;    // 128 floats
    float* POOL = SUMS + 128;                       // 16384 floats
    float* CNT  = POOL + N_GRAPHS * 64;             // 256 floats

    const int scatter_blocks = (N_EDGES * 16) / 256;      // 62500
    const int elem_blocks    = (N_NODES * 16) / 256;      // 6250

    for (int L = 0; L < 3; ++L) {
        const float* xin = (L == 0) ? x0 : X;
        hipMemsetAsync(A, 0, (size_t)N_NODES * 64 * sizeof(float), stream);
        hipMemsetAsync(SUMS, 0, 128 * sizeof(float), stream);
        scatter_kernel<<<scatter_blocks, 256, 0, stream>>>(xin, ei, A);
        mlp_kernel<<<768, 256, 0, stream>>>(xin, A,
                                            w1 + L * 4096, b1 + L * 64,
                                            w2 + L * 4096, b2 + L * 64,
                                            eps_g, L, SUMS);
        bn_kernel<<<elem_blocks, 256, 0, stream>>>(
            (const float4*)A, SUMS, gamma + L * 64, beta + L * 64, (float4*)X);
    }

    hipMemsetAsync(POOL, 0, (N_GRAPHS * 64 + N_GRAPHS) * sizeof(float), stream);
    pool_kernel<<<elem_blocks, 256, 0, stream>>>((const float4*)X, batch, POOL, CNT);
    final_kernel<<<(N_GRAPHS * OUT_DIM + 255) / 256, 256, 0, stream>>>(
        POOL, CNT, lin_w, lin_b, out);
}

// Round 2
// 1086.247 us; speedup vs baseline: 3.0625x; 3.0625x over previous
//
#include <hip/hip_runtime.h>
#include <hip/hip_bf16.h>

#define N_NODES 100000
#define N_EDGES 1000000
#define DIM 64
#define N_GRAPHS 256
#define OUT_DIM 10
#define BN_EPS 1e-5f

#define SCAN_NBLK ((N_NODES + 255) / 256)   // 391

// ---------------------------------------------------------------------------
// CSR build step 1: degree histogram over dst.
// ---------------------------------------------------------------------------
__global__ __launch_bounds__(256) void hist_kernel(
    const int* __restrict__ ei, int* __restrict__ deg)
{
    int e = blockIdx.x * 256 + threadIdx.x;
    if (e >= N_EDGES) return;
    atomicAdd(&deg[ei[N_EDGES + e]], 1);
}

// ---------------------------------------------------------------------------
// CSR build step 2a: per-256-block sums of deg.
// ---------------------------------------------------------------------------
__global__ __launch_bounds__(256) void block_sum_kernel(
    const int* __restrict__ deg, int* __restrict__ bsum)
{
    __shared__ int red[4];
    int t = threadIdx.x;
    int i = blockIdx.x * 256 + t;
    int v = (i < N_NODES) ? deg[i] : 0;
#pragma unroll
    for (int off = 32; off; off >>= 1) v += __shfl_down(v, off, 64);
    if ((t & 63) == 0) red[t >> 6] = v;
    __syncthreads();
    if (t == 0) bsum[blockIdx.x] = red[0] + red[1] + red[2] + red[3];
}

// ---------------------------------------------------------------------------
// CSR build step 2b: exclusive scan of the 391 block sums (single block).
// ---------------------------------------------------------------------------
__global__ __launch_bounds__(512) void scan_partials_kernel(int* __restrict__ bsum)
{
    __shared__ int s[512];
    int t = threadIdx.x;
    s[t] = (t < SCAN_NBLK) ? bsum[t] : 0;
    __syncthreads();
#pragma unroll
    for (int off = 1; off < 512; off <<= 1) {
        int v = s[t];
        if (t >= off) v += s[t - off];
        __syncthreads();
        s[t] = v;
        __syncthreads();
    }
    if (t < SCAN_NBLK) bsum[t] = (t == 0) ? 0 : s[t - 1];
}

// ---------------------------------------------------------------------------
// CSR build step 2c: per-block exclusive scan + block offset -> start, cursor.
// ---------------------------------------------------------------------------
__global__ __launch_bounds__(256) void scan_final_kernel(
    const int* __restrict__ deg, const int* __restrict__ bsum,
    int* __restrict__ start, int* __restrict__ cursor)
{
    __shared__ int s[256];
    int t = threadIdx.x;
    int i = blockIdx.x * 256 + t;
    int v = (i < N_NODES) ? deg[i] : 0;
    s[t] = v;
    __syncthreads();
#pragma unroll
    for (int off = 1; off < 256; off <<= 1) {
        int u = s[t];
        if (t >= off) u += s[t - off];
        __syncthreads();
        s[t] = u;
        __syncthreads();
    }
    if (i < N_NODES) {
        int excl = s[t] - v + bsum[blockIdx.x];
        start[i] = excl;
        cursor[i] = excl;
    }
}

// ---------------------------------------------------------------------------
// CSR build step 3: bucket src ids by dst.
// ---------------------------------------------------------------------------
__global__ __launch_bounds__(256) void bucket_kernel(
    const int* __restrict__ ei, int* __restrict__ cursor,
    int* __restrict__ esrc)
{
    int e = blockIdx.x * 256 + threadIdx.x;
    if (e >= N_EDGES) return;
    int pos = atomicAdd(&cursor[ei[N_EDGES + e]], 1);
    esrc[pos] = ei[e];
}

// ---------------------------------------------------------------------------
// Gather aggregation: one wave per node, lane = dim.
// agg[n][lane] = sum over incoming edges of x[src][lane]. No atomics.
// ---------------------------------------------------------------------------
__global__ __launch_bounds__(256) void gather_kernel(
    const float* __restrict__ x, const int* __restrict__ start,
    const int* __restrict__ deg, const int* __restrict__ esrc,
    float* __restrict__ agg)
{
    const int lane = threadIdx.x & 63;
    const int n = blockIdx.x * 4 + (threadIdx.x >> 6);
    if (n >= N_NODES) return;
    const int s = start[n];
    const int d = deg[n];
    float sum = 0.0f;
    int j = 0;
    for (; j + 1 < d; j += 2) {
        int s0 = esrc[s + j];
        int s1 = esrc[s + j + 1];
        sum += x[s0 * 64 + lane];
        sum += x[s1 * 64 + lane];
    }
    if (j < d) sum += x[esrc[s + j] * 64 + lane];
    agg[n * 64 + lane] = sum;
}

// ---------------------------------------------------------------------------
// Fused GIN MLP: h = (1+eps)*x + agg ; h1 = relu(h@w1+b1) ; h2 = relu(h1@w2+b2)
// Writes h2 in-place over agg, accumulates BN sum/sumsq per dim.
// One wave per node; lane = output dim. W held in VGPRs (w[:,lane] per lane),
// activation broadcast via v_readlane -> pure-VALU inner loop (no LDS pipe).
// ---------------------------------------------------------------------------
__global__ __launch_bounds__(256) void mlp_kernel(
    const float* __restrict__ x, float* __restrict__ h2buf,
    const float* __restrict__ w1, const float* __restrict__ b1,
    const float* __restrict__ w2, const float* __restrict__ b2,
    const float* __restrict__ eps_all, int layer,
    float* __restrict__ sums)
{
    const int lane = threadIdx.x & 63;
    const int wave = blockIdx.x * 4 + (threadIdx.x >> 6);
    const int nwaves = gridDim.x * 4;

    float w1r[64], w2r[64];
#pragma unroll
    for (int k = 0; k < 64; ++k) w1r[k] = w1[k * 64 + lane];  // coalesced
#pragma unroll
    for (int k = 0; k < 64; ++k) w2r[k] = w2[k * 64 + lane];
    const float b1v = b1[lane];
    const float b2v = b2[lane];
    const float epsv = 1.0f + eps_all[layer];

    float lsum = 0.0f, lsq = 0.0f;

    for (int n = wave; n < N_NODES; n += nwaves) {
        float xv = x[n * 64 + lane];
        float av = h2buf[n * 64 + lane];
        float h = fmaf(epsv, xv, av);

        float acc = b1v;
#pragma unroll
        for (int k = 0; k < 64; ++k) {
            float hk = __int_as_float(
                __builtin_amdgcn_readlane(__float_as_int(h), k));
            acc = fmaf(hk, w1r[k], acc);
        }
        float h1 = fmaxf(acc, 0.0f);

        float acc2 = b2v;
#pragma unroll
        for (int k = 0; k < 64; ++k) {
            float hk = __int_as_float(
                __builtin_amdgcn_readlane(__float_as_int(h1), k));
            acc2 = fmaf(hk, w2r[k], acc2);
        }
        float v = fmaxf(acc2, 0.0f);

        h2buf[n * 64 + lane] = v;
        lsum += v;
        lsq = fmaf(v, v, lsq);
    }
    unsafeAtomicAdd(&sums[lane], lsum);
    unsafeAtomicAdd(&sums[64 + lane], lsq);
}

// ---------------------------------------------------------------------------
// BatchNorm (training-mode batch stats, biased var) + ReLU, elementwise.
// ---------------------------------------------------------------------------
__global__ __launch_bounds__(256) void bn_kernel(
    const float4* __restrict__ h2, const float* __restrict__ sums,
    const float* __restrict__ gamma, const float* __restrict__ beta,
    float4* __restrict__ xo)
{
    int t = blockIdx.x * 256 + threadIdx.x;
    if (t >= N_NODES * 16) return;
    int q = t & 15;
    int d = q * 4;
    const float inv_n = 1.0f / (float)N_NODES;
    float4 v = h2[t];
    float4 o;
    float* vp = (float*)&v;
    float* op = (float*)&o;
#pragma unroll
    for (int j = 0; j < 4; ++j) {
        int dd = d + j;
        float mean = sums[dd] * inv_n;
        float m2 = sums[64 + dd] * inv_n;
        float var = m2 - mean * mean;
        float scale = gamma[dd] * rsqrtf(var + BN_EPS);
        float shift = fmaf(-mean, scale, beta[dd]);
        op[j] = fmaxf(fmaf(vp[j], scale, shift), 0.0f);
    }
    xo[t] = o;
}

// ---------------------------------------------------------------------------
// Global mean pool (atomic accumulate; 256 graphs * 64 dims of targets).
// ---------------------------------------------------------------------------
__global__ __launch_bounds__(256) void pool_kernel(
    const float4* __restrict__ x, const int* __restrict__ batch,
    float* __restrict__ pooled, float* __restrict__ counts)
{
    int t = blockIdx.x * 256 + threadIdx.x;
    if (t >= N_NODES * 16) return;
    int n = t >> 4;
    int q = t & 15;
    int g = batch[n];
    float4 v = x[t];
    float* p = pooled + g * 64 + q * 4;
    unsafeAtomicAdd(p + 0, v.x);
    unsafeAtomicAdd(p + 1, v.y);
    unsafeAtomicAdd(p + 2, v.z);
    unsafeAtomicAdd(p + 3, v.w);
    if (q == 0) unsafeAtomicAdd(&counts[g], 1.0f);
}

// ---------------------------------------------------------------------------
// Final linear: out[g][o] = (sum_d pooled[g][d]*lin_w[d][o]) / max(cnt,1) + b[o]
// ---------------------------------------------------------------------------
__global__ __launch_bounds__(256) void final_kernel(
    const float* __restrict__ pooled, const float* __restrict__ counts,
    const float* __restrict__ lin_w, const float* __restrict__ lin_b,
    float* __restrict__ out)
{
    int t = blockIdx.x * 256 + threadIdx.x;
    if (t >= N_GRAPHS * OUT_DIM) return;
    int g = t / OUT_DIM;
    int o = t - g * OUT_DIM;
    float acc = 0.0f;
#pragma unroll 8
    for (int d = 0; d < 64; ++d)
        acc = fmaf(pooled[g * 64 + d], lin_w[d * OUT_DIM + o], acc);
    float c = fmaxf(counts[g], 1.0f);
    out[t] = acc / c + lin_b[o];
}

extern "C" void kernel_launch(void* const* d_in, const int* in_sizes, int n_in,
                              void* d_out, int out_size, void* d_ws, size_t ws_size,
                              hipStream_t stream)
{
    const float* x0    = (const float*)d_in[0];
    const int*   ei    = (const int*)d_in[1];
    const int*   batch = (const int*)d_in[2];
    const float* w1    = (const float*)d_in[3];
    const float* b1    = (const float*)d_in[4];
    const float* w2    = (const float*)d_in[5];
    const float* b2    = (const float*)d_in[6];
    const float* gamma = (const float*)d_in[7];
    const float* beta  = (const float*)d_in[8];
    const float* eps_g = (const float*)d_in[9];
    const float* lin_w = (const float*)d_in[10];
    const float* lin_b = (const float*)d_in[11];
    float* out = (float*)d_out;

    // Workspace layout (floats then ints).
    float* ws   = (float*)d_ws;
    float* A    = ws;                                // agg -> h2, 6.4M floats
    float* X    = ws + (size_t)N_NODES * 64;         // layer output, 6.4M floats
    float* SUMS = ws + (size_t)2 * N_NODES * 64;     // 128
    float* POOL = SUMS + 128;                        // 16384
    float* CNT  = POOL + N_GRAPHS * 64;              // 256
    int*   ibase  = (int*)(CNT + N_GRAPHS);
    int*   DEG    = ibase;                            // 100000
    int*   START  = ibase + N_NODES;                  // 100000
    int*   CURSOR = ibase + 2 * N_NODES;              // 100000
    int*   BSUM   = ibase + 3 * N_NODES;              // 512
    int*   ESRC   = ibase + 3 * N_NODES + 512;        // 1000000

    const int edge_blocks = (N_EDGES + 255) / 256;    // 3907
    const int elem_blocks = (N_NODES * 16) / 256;     // 6250
    const int node_wave_blocks = (N_NODES + 3) / 4;   // 25000

    // ---- CSR build (once per call; ws is re-poisoned every launch) ----
    hipMemsetAsync(DEG, 0, N_NODES * sizeof(int), stream);
    hist_kernel<<<edge_blocks, 256, 0, stream>>>(ei, DEG);
    block_sum_kernel<<<SCAN_NBLK, 256, 0, stream>>>(DEG, BSUM);
    scan_partials_kernel<<<1, 512, 0, stream>>>(BSUM);
    scan_final_kernel<<<SCAN_NBLK, 256, 0, stream>>>(DEG, BSUM, START, CURSOR);
    bucket_kernel<<<edge_blocks, 256, 0, stream>>>(ei, CURSOR, ESRC);

    // ---- 3 GIN layers ----
    for (int L = 0; L < 3; ++L) {
        const float* xin = (L == 0) ? x0 : X;
        hipMemsetAsync(SUMS, 0, 128 * sizeof(float), stream);
        gather_kernel<<<node_wave_blocks, 256, 0, stream>>>(xin, START, DEG, ESRC, A);
        mlp_kernel<<<768, 256, 0, stream>>>(xin, A,
                                            w1 + L * 4096, b1 + L * 64,
                                            w2 + L * 4096, b2 + L * 64,
                                            eps_g, L, SUMS);
        bn_kernel<<<elem_blocks, 256, 0, stream>>>(
            (const float4*)A, SUMS, gamma + L * 64, beta + L * 64, (float4*)X);
    }

    // ---- pool + linear ----
    hipMemsetAsync(POOL, 0, (N_GRAPHS * 64 + N_GRAPHS) * sizeof(float), stream);
    pool_kernel<<<elem_blocks, 256, 0, stream>>>((const float4*)X, batch, POOL, CNT);
    final_kernel<<<(N_GRAPHS * OUT_DIM + 255) / 256, 256, 0, stream>>>(
        POOL, CNT, lin_w, lin_b, out);
}

// Round 3
// 731.661 us; speedup vs baseline: 4.5467x; 1.4846x over previous
//
#include <hip/hip_runtime.h>
#include <hip/hip_bf16.h>

#define N_NODES 100000
#define N_EDGES 1000000
#define DIM 64
#define N_GRAPHS 256
#define OUT_DIM 10
#define BN_EPS 1e-5f

#define SCAN_NBLK ((N_NODES + 255) / 256)   // 391
#define POOL_BLOCKS 512                      // 2048 waves

// ---------------------------------------------------------------------------
// CSR build step 1: degree histogram over dst.
// ---------------------------------------------------------------------------
__global__ __launch_bounds__(256) void hist_kernel(
    const int* __restrict__ ei, int* __restrict__ deg)
{
    int e = blockIdx.x * 256 + threadIdx.x;
    if (e >= N_EDGES) return;
    atomicAdd(&deg[ei[N_EDGES + e]], 1);
}

// ---------------------------------------------------------------------------
// CSR build step 2a: per-256-block sums of deg.
// ---------------------------------------------------------------------------
__global__ __launch_bounds__(256) void block_sum_kernel(
    const int* __restrict__ deg, int* __restrict__ bsum)
{
    __shared__ int red[4];
    int t = threadIdx.x;
    int i = blockIdx.x * 256 + t;
    int v = (i < N_NODES) ? deg[i] : 0;
#pragma unroll
    for (int off = 32; off; off >>= 1) v += __shfl_down(v, off, 64);
    if ((t & 63) == 0) red[t >> 6] = v;
    __syncthreads();
    if (t == 0) bsum[blockIdx.x] = red[0] + red[1] + red[2] + red[3];
}

// ---------------------------------------------------------------------------
// CSR build step 2b: exclusive scan of the 391 block sums (single block).
// ---------------------------------------------------------------------------
__global__ __launch_bounds__(512) void scan_partials_kernel(int* __restrict__ bsum)
{
    __shared__ int s[512];
    int t = threadIdx.x;
    s[t] = (t < SCAN_NBLK) ? bsum[t] : 0;
    __syncthreads();
#pragma unroll
    for (int off = 1; off < 512; off <<= 1) {
        int v = s[t];
        if (t >= off) v += s[t - off];
        __syncthreads();
        s[t] = v;
        __syncthreads();
    }
    if (t < SCAN_NBLK) bsum[t] = (t == 0) ? 0 : s[t - 1];
}

// ---------------------------------------------------------------------------
// CSR build step 2c: per-block exclusive scan + block offset -> start, cursor.
// ---------------------------------------------------------------------------
__global__ __launch_bounds__(256) void scan_final_kernel(
    const int* __restrict__ deg, const int* __restrict__ bsum,
    int* __restrict__ start, int* __restrict__ cursor)
{
    __shared__ int s[256];
    int t = threadIdx.x;
    int i = blockIdx.x * 256 + t;
    int v = (i < N_NODES) ? deg[i] : 0;
    s[t] = v;
    __syncthreads();
#pragma unroll
    for (int off = 1; off < 256; off <<= 1) {
        int u = s[t];
        if (t >= off) u += s[t - off];
        __syncthreads();
        s[t] = u;
        __syncthreads();
    }
    if (i < N_NODES) {
        int excl = s[t] - v + bsum[blockIdx.x];
        start[i] = excl;
        cursor[i] = excl;
    }
}

// ---------------------------------------------------------------------------
// CSR build step 3: bucket src ids by dst.
// ---------------------------------------------------------------------------
__global__ __launch_bounds__(256) void bucket_kernel(
    const int* __restrict__ ei, int* __restrict__ cursor,
    int* __restrict__ esrc)
{
    int e = blockIdx.x * 256 + threadIdx.x;
    if (e >= N_EDGES) return;
    int pos = atomicAdd(&cursor[ei[N_EDGES + e]], 1);
    esrc[pos] = ei[e];
}

// ---------------------------------------------------------------------------
// BN prep: per-dim affine from accumulated sum/sumsq.
// sc[0..63] = scale, sc[64..127] = shift.  y = relu(scale*v + shift)
// ---------------------------------------------------------------------------
__global__ __launch_bounds__(64) void bnprep_kernel(
    const float* __restrict__ sums, const float* __restrict__ gamma,
    const float* __restrict__ beta, float* __restrict__ sc)
{
    int d = threadIdx.x;
    const float inv_n = 1.0f / (float)N_NODES;
    float mean = sums[d] * inv_n;
    float m2 = sums[64 + d] * inv_n;
    float var = m2 - mean * mean;
    float scale = gamma[d] * rsqrtf(var + BN_EPS);
    sc[d] = scale;
    sc[64 + d] = fmaf(-mean, scale, beta[d]);
}

// ---------------------------------------------------------------------------
// Gather aggregation: one wave per node, lane = dim. Optionally applies the
// previous layer's BN affine + relu to each gathered value (fused bn_kernel).
// ---------------------------------------------------------------------------
template <bool BN>
__global__ __launch_bounds__(256) void gather_kernel(
    const float* __restrict__ x, const float* __restrict__ sc,
    const int* __restrict__ start, const int* __restrict__ deg,
    const int* __restrict__ esrc, float* __restrict__ agg)
{
    const int lane = threadIdx.x & 63;
    const int n = blockIdx.x * 4 + (threadIdx.x >> 6);
    if (n >= N_NODES) return;
    float scale = 1.0f, shift = 0.0f;
    if (BN) { scale = sc[lane]; shift = sc[64 + lane]; }
    const int s = start[n];
    const int d = deg[n];
    float sum = 0.0f;
    int j = 0;
    for (; j + 3 < d; j += 4) {
        int s0 = esrc[s + j];
        int s1 = esrc[s + j + 1];
        int s2 = esrc[s + j + 2];
        int s3 = esrc[s + j + 3];
        float v0 = x[s0 * 64 + lane];
        float v1 = x[s1 * 64 + lane];
        float v2 = x[s2 * 64 + lane];
        float v3 = x[s3 * 64 + lane];
        if (BN) {
            v0 = fmaxf(fmaf(v0, scale, shift), 0.0f);
            v1 = fmaxf(fmaf(v1, scale, shift), 0.0f);
            v2 = fmaxf(fmaf(v2, scale, shift), 0.0f);
            v3 = fmaxf(fmaf(v3, scale, shift), 0.0f);
        }
        sum += (v0 + v1) + (v2 + v3);
    }
    for (; j < d; ++j) {
        float v = x[esrc[s + j] * 64 + lane];
        if (BN) v = fmaxf(fmaf(v, scale, shift), 0.0f);
        sum += v;
    }
    agg[n * 64 + lane] = sum;
}

// ---------------------------------------------------------------------------
// Fused GIN MLP. Optionally applies previous layer's BN affine+relu to the
// self-term x. h2 written in place over agg; accumulates BN sum/sumsq.
// ---------------------------------------------------------------------------
template <bool BN>
__global__ __launch_bounds__(256) void mlp_kernel(
    const float* __restrict__ x, const float* __restrict__ sc,
    float* __restrict__ h2buf,
    const float* __restrict__ w1, const float* __restrict__ b1,
    const float* __restrict__ w2, const float* __restrict__ b2,
    const float* __restrict__ eps_all, int layer,
    float* __restrict__ sums)
{
    const int lane = threadIdx.x & 63;
    const int wave = blockIdx.x * 4 + (threadIdx.x >> 6);
    const int nwaves = gridDim.x * 4;

    float w1r[64], w2r[64];
#pragma unroll
    for (int k = 0; k < 64; ++k) w1r[k] = w1[k * 64 + lane];  // coalesced
#pragma unroll
    for (int k = 0; k < 64; ++k) w2r[k] = w2[k * 64 + lane];
    const float b1v = b1[lane];
    const float b2v = b2[lane];
    const float epsv = 1.0f + eps_all[layer];
    float scale = 1.0f, shift = 0.0f;
    if (BN) { scale = sc[lane]; shift = sc[64 + lane]; }

    float lsum = 0.0f, lsq = 0.0f;

    for (int n = wave; n < N_NODES; n += nwaves) {
        float xv = x[n * 64 + lane];
        if (BN) xv = fmaxf(fmaf(xv, scale, shift), 0.0f);
        float av = h2buf[n * 64 + lane];
        float h = fmaf(epsv, xv, av);

        float acc = b1v;
#pragma unroll
        for (int k = 0; k < 64; ++k) {
            float hk = __int_as_float(
                __builtin_amdgcn_readlane(__float_as_int(h), k));
            acc = fmaf(hk, w1r[k], acc);
        }
        float h1 = fmaxf(acc, 0.0f);

        float acc2 = b2v;
#pragma unroll
        for (int k = 0; k < 64; ++k) {
            float hk = __int_as_float(
                __builtin_amdgcn_readlane(__float_as_int(h1), k));
            acc2 = fmaf(hk, w2r[k], acc2);
        }
        float v = fmaxf(acc2, 0.0f);

        h2buf[n * 64 + lane] = v;
        lsum += v;
        lsq = fmaf(v, v, lsq);
    }
    unsafeAtomicAdd(&sums[lane], lsum);
    unsafeAtomicAdd(&sums[64 + lane], lsq);
}

// ---------------------------------------------------------------------------
// Segmented global mean pool. batch is SORTED: each wave takes a contiguous
// node chunk (lane = dim), register-accumulates per graph, one atomic flush
// per graph-boundary crossing. Applies last layer's BN affine+relu on load.
// ---------------------------------------------------------------------------
__global__ __launch_bounds__(256) void pool_kernel(
    const float* __restrict__ h2, const float* __restrict__ sc,
    const int* __restrict__ batch,
    float* __restrict__ pooled, float* __restrict__ counts)
{
    const int lane = threadIdx.x & 63;
    const int w = blockIdx.x * 4 + (threadIdx.x >> 6);
    const int nw = POOL_BLOCKS * 4;
    const int npw = (N_NODES + nw - 1) / nw;
    int n0 = w * npw;
    if (n0 >= N_NODES) return;
    int n1 = n0 + npw;
    if (n1 > N_NODES) n1 = N_NODES;

    const float scale = sc[lane];
    const float shift = sc[64 + lane];

    int cur = batch[n0];
    float acc = 0.0f, cnt = 0.0f;
    for (int n = n0; n < n1; ++n) {
        int g = batch[n];                       // wave-uniform
        if (g != cur) {                         // wave-uniform branch
            unsafeAtomicAdd(&pooled[cur * 64 + lane], acc);
            if (lane == 0) unsafeAtomicAdd(&counts[cur], cnt);
            acc = 0.0f; cnt = 0.0f; cur = g;
        }
        float v = h2[n * 64 + lane];
        v = fmaxf(fmaf(v, scale, shift), 0.0f);
        acc += v;
        cnt += 1.0f;
    }
    unsafeAtomicAdd(&pooled[cur * 64 + lane], acc);
    if (lane == 0) unsafeAtomicAdd(&counts[cur], cnt);
}

// ---------------------------------------------------------------------------
// Final linear: out[g][o] = (sum_d pooled[g][d]*lin_w[d][o]) / max(cnt,1) + b[o]
// ---------------------------------------------------------------------------
__global__ __launch_bounds__(256) void final_kernel(
    const float* __restrict__ pooled, const float* __restrict__ counts,
    const float* __restrict__ lin_w, const float* __restrict__ lin_b,
    float* __restrict__ out)
{
    int t = blockIdx.x * 256 + threadIdx.x;
    if (t >= N_GRAPHS * OUT_DIM) return;
    int g = t / OUT_DIM;
    int o = t - g * OUT_DIM;
    float acc = 0.0f;
#pragma unroll 8
    for (int d = 0; d < 64; ++d)
        acc = fmaf(pooled[g * 64 + d], lin_w[d * OUT_DIM + o], acc);
    float c = fmaxf(counts[g], 1.0f);
    out[t] = acc / c + lin_b[o];
}

extern "C" void kernel_launch(void* const* d_in, const int* in_sizes, int n_in,
                              void* d_out, int out_size, void* d_ws, size_t ws_size,
                              hipStream_t stream)
{
    const float* x0    = (const float*)d_in[0];
    const int*   ei    = (const int*)d_in[1];
    const int*   batch = (const int*)d_in[2];
    const float* w1    = (const float*)d_in[3];
    const float* b1    = (const float*)d_in[4];
    const float* w2    = (const float*)d_in[5];
    const float* b2    = (const float*)d_in[6];
    const float* gamma = (const float*)d_in[7];
    const float* beta  = (const float*)d_in[8];
    const float* eps_g = (const float*)d_in[9];
    const float* lin_w = (const float*)d_in[10];
    const float* lin_b = (const float*)d_in[11];
    float* out = (float*)d_out;

    // Workspace layout.
    float* ws   = (float*)d_ws;
    float* A    = ws;                                // ping, 6.4M floats
    float* B    = ws + (size_t)N_NODES * 64;         // pong, 6.4M floats
    float* SUMS = ws + (size_t)2 * N_NODES * 64;     // 128
    float* SC   = SUMS + 128;                        // 3 * 128 (scale|shift)
    float* POOL = SC + 3 * 128;                      // 16384
    float* CNT  = POOL + N_GRAPHS * 64;              // 256
    int*   ibase  = (int*)(CNT + N_GRAPHS);
    int*   DEG    = ibase;                            // 100000
    int*   START  = ibase + N_NODES;                  // 100000
    int*   CURSOR = ibase + 2 * N_NODES;              // 100000
    int*   BSUM   = ibase + 3 * N_NODES;              // 512
    int*   ESRC   = ibase + 3 * N_NODES + 512;        // 1000000

    const int edge_blocks = (N_EDGES + 255) / 256;    // 3907
    const int node_wave_blocks = (N_NODES + 3) / 4;   // 25000

    // ---- CSR build (once per call; ws re-poisoned every launch) ----
    hipMemsetAsync(DEG, 0, N_NODES * sizeof(int), stream);
    hist_kernel<<<edge_blocks, 256, 0, stream>>>(ei, DEG);
    block_sum_kernel<<<SCAN_NBLK, 256, 0, stream>>>(DEG, BSUM);
    scan_partials_kernel<<<1, 512, 0, stream>>>(BSUM);
    scan_final_kernel<<<SCAN_NBLK, 256, 0, stream>>>(DEG, BSUM, START, CURSOR);
    bucket_kernel<<<edge_blocks, 256, 0, stream>>>(ei, CURSOR, ESRC);

    // ---- 3 GIN layers (BN of layer L fused into consumers of layer L+1) ----
    // L0: x0 -> agg in A -> h2_0 in A
    hipMemsetAsync(SUMS, 0, 128 * sizeof(float), stream);
    gather_kernel<false><<<node_wave_blocks, 256, 0, stream>>>(
        x0, nullptr, START, DEG, ESRC, A);
    mlp_kernel<false><<<768, 256, 0, stream>>>(
        x0, nullptr, A, w1, b1, w2, b2, eps_g, 0, SUMS);
    bnprep_kernel<<<1, 64, 0, stream>>>(SUMS, gamma, beta, SC);

    // L1: bn(A) -> agg in B -> h2_1 in B
    hipMemsetAsync(SUMS, 0, 128 * sizeof(float), stream);
    gather_kernel<true><<<node_wave_blocks, 256, 0, stream>>>(
        A, SC, START, DEG, ESRC, B);
    mlp_kernel<true><<<768, 256, 0, stream>>>(
        A, SC, B, w1 + 4096, b1 + 64, w2 + 4096, b2 + 64, eps_g, 1, SUMS);
    bnprep_kernel<<<1, 64, 0, stream>>>(SUMS, gamma + 64, beta + 64, SC + 128);

    // L2: bn(B) -> agg in A -> h2_2 in A
    hipMemsetAsync(SUMS, 0, 128 * sizeof(float), stream);
    gather_kernel<true><<<node_wave_blocks, 256, 0, stream>>>(
        B, SC + 128, START, DEG, ESRC, A);
    mlp_kernel<true><<<768, 256, 0, stream>>>(
        B, SC + 128, A, w1 + 8192, b1 + 128, w2 + 8192, b2 + 128, eps_g, 2, SUMS);
    bnprep_kernel<<<1, 64, 0, stream>>>(SUMS, gamma + 128, beta + 128, SC + 256);

    // ---- segmented pool (applies bn of L2) + linear ----
    hipMemsetAsync(POOL, 0, (N_GRAPHS * 64 + N_GRAPHS) * sizeof(float), stream);
    pool_kernel<<<POOL_BLOCKS, 256, 0, stream>>>(A, SC + 256, batch, POOL, CNT);
    final_kernel<<<(N_GRAPHS * OUT_DIM + 255) / 256, 256, 0, stream>>>(
        POOL, CNT, lin_w, lin_b, out);
}

// Round 4
// 543.996 us; speedup vs baseline: 6.1152x; 1.3450x over previous
//
#include <hip/hip_runtime.h>
#include <hip/hip_bf16.h>

#define N_NODES 100000
#define N_EDGES 1000000
#define DIM 64
#define N_GRAPHS 256
#define OUT_DIM 10
#define BN_EPS 1e-5f

#define SCAN_NBLK ((N_NODES + 255) / 256)   // 391
#define POOL_BLOCKS 512                      // 2048 waves
#define MLP_BLOCKS ((N_NODES + 63) / 64)     // 1563

typedef __bf16 bf16x8 __attribute__((ext_vector_type(8)));
typedef float f32x4 __attribute__((ext_vector_type(4)));

// ---------------------------------------------------------------------------
// CSR build step 1: degree histogram over dst.
// ---------------------------------------------------------------------------
__global__ __launch_bounds__(256) void hist_kernel(
    const int* __restrict__ ei, int* __restrict__ deg)
{
    int e = blockIdx.x * 256 + threadIdx.x;
    if (e >= N_EDGES) return;
    atomicAdd(&deg[ei[N_EDGES + e]], 1);
}

// ---------------------------------------------------------------------------
// CSR build step 2a: per-256-block sums of deg.
// ---------------------------------------------------------------------------
__global__ __launch_bounds__(256) void block_sum_kernel(
    const int* __restrict__ deg, int* __restrict__ bsum)
{
    __shared__ int red[4];
    int t = threadIdx.x;
    int i = blockIdx.x * 256 + t;
    int v = (i < N_NODES) ? deg[i] : 0;
#pragma unroll
    for (int off = 32; off; off >>= 1) v += __shfl_down(v, off, 64);
    if ((t & 63) == 0) red[t >> 6] = v;
    __syncthreads();
    if (t == 0) bsum[blockIdx.x] = red[0] + red[1] + red[2] + red[3];
}

// ---------------------------------------------------------------------------
// CSR build step 2b: exclusive scan of the 391 block sums (single block).
// ---------------------------------------------------------------------------
__global__ __launch_bounds__(512) void scan_partials_kernel(int* __restrict__ bsum)
{
    __shared__ int s[512];
    int t = threadIdx.x;
    s[t] = (t < SCAN_NBLK) ? bsum[t] : 0;
    __syncthreads();
#pragma unroll
    for (int off = 1; off < 512; off <<= 1) {
        int v = s[t];
        if (t >= off) v += s[t - off];
        __syncthreads();
        s[t] = v;
        __syncthreads();
    }
    if (t < SCAN_NBLK) bsum[t] = (t == 0) ? 0 : s[t - 1];
}

// ---------------------------------------------------------------------------
// CSR build step 2c: per-block exclusive scan + block offset -> start, cursor.
// ---------------------------------------------------------------------------
__global__ __launch_bounds__(256) void scan_final_kernel(
    const int* __restrict__ deg, const int* __restrict__ bsum,
    int* __restrict__ start, int* __restrict__ cursor)
{
    __shared__ int s[256];
    int t = threadIdx.x;
    int i = blockIdx.x * 256 + t;
    int v = (i < N_NODES) ? deg[i] : 0;
    s[t] = v;
    __syncthreads();
#pragma unroll
    for (int off = 1; off < 256; off <<= 1) {
        int u = s[t];
        if (t >= off) u += s[t - off];
        __syncthreads();
        s[t] = u;
        __syncthreads();
    }
    if (i < N_NODES) {
        int excl = s[t] - v + bsum[blockIdx.x];
        start[i] = excl;
        cursor[i] = excl;
    }
}

// ---------------------------------------------------------------------------
// CSR build step 3: bucket src ids by dst.
// ---------------------------------------------------------------------------
__global__ __launch_bounds__(256) void bucket_kernel(
    const int* __restrict__ ei, int* __restrict__ cursor,
    int* __restrict__ esrc)
{
    int e = blockIdx.x * 256 + threadIdx.x;
    if (e >= N_EDGES) return;
    int pos = atomicAdd(&cursor[ei[N_EDGES + e]], 1);
    esrc[pos] = ei[e];
}

// ---------------------------------------------------------------------------
// BN prep: per-dim affine from accumulated sum/sumsq.
// sc[0..63] = scale, sc[64..127] = shift.  y = relu(scale*v + shift)
// ---------------------------------------------------------------------------
__global__ __launch_bounds__(64) void bnprep_kernel(
    const float* __restrict__ sums, const float* __restrict__ gamma,
    const float* __restrict__ beta, float* __restrict__ sc)
{
    int d = threadIdx.x;
    const float inv_n = 1.0f / (float)N_NODES;
    float mean = sums[d] * inv_n;
    float m2 = sums[64 + d] * inv_n;
    float var = m2 - mean * mean;
    float scale = gamma[d] * rsqrtf(var + BN_EPS);
    sc[d] = scale;
    sc[64 + d] = fmaf(-mean, scale, beta[d]);
}

// ---------------------------------------------------------------------------
// Weight prep: split each 64x64 fp32 W into bf16 hi/lo, stored in MFMA
// B-fragment order: blob[(kstep*4+ntile)*64 + lane][j]; hi at +0, lo at +4096.
// B[k][n]: n = lane&15, k = kstep*32 + (lane>>4)*8 + j.
// One block per (layer, mat): blockIdx.x = L*2 + mat.
// ---------------------------------------------------------------------------
__global__ __launch_bounds__(256) void wprep_kernel(
    const float* __restrict__ w1, const float* __restrict__ w2,
    __bf16* __restrict__ wf)
{
    int L = blockIdx.x >> 1, mat = blockIdx.x & 1;
    const float* w = (mat ? w2 : w1) + L * 4096;
    __bf16* dst = wf + blockIdx.x * 8192;
#pragma unroll
    for (int r = 0; r < 2; ++r) {
        int idx = threadIdx.x + 256 * r;          // (kstep*4+nt)*64 + lane
        int lane = idx & 63;
        int kt = idx >> 6;
        int kstep = kt >> 2, nt = kt & 3;
        int n = nt * 16 + (lane & 15);
        int kbase = kstep * 32 + (lane >> 4) * 8;
#pragma unroll
        for (int j = 0; j < 8; ++j) {
            float v = w[(kbase + j) * 64 + n];
            __bf16 hi = (__bf16)v;
            dst[idx * 8 + j] = hi;
            dst[4096 + idx * 8 + j] = (__bf16)(v - (float)hi);
        }
    }
}

// ---------------------------------------------------------------------------
// Gather aggregation: one wave per node, lane = dim. Optionally applies the
// previous layer's BN affine + relu to each gathered value.
// ---------------------------------------------------------------------------
template <bool BN>
__global__ __launch_bounds__(256) void gather_kernel(
    const float* __restrict__ x, const float* __restrict__ sc,
    const int* __restrict__ start, const int* __restrict__ deg,
    const int* __restrict__ esrc, float* __restrict__ agg)
{
    const int lane = threadIdx.x & 63;
    const int n = blockIdx.x * 4 + (threadIdx.x >> 6);
    if (n >= N_NODES) return;
    float scale = 1.0f, shift = 0.0f;
    if (BN) { scale = sc[lane]; shift = sc[64 + lane]; }
    const int s = start[n];
    const int d = deg[n];
    float sum = 0.0f;
    int j = 0;
    for (; j + 3 < d; j += 4) {
        int s0 = esrc[s + j];
        int s1 = esrc[s + j + 1];
        int s2 = esrc[s + j + 2];
        int s3 = esrc[s + j + 3];
        float v0 = x[s0 * 64 + lane];
        float v1 = x[s1 * 64 + lane];
        float v2 = x[s2 * 64 + lane];
        float v3 = x[s3 * 64 + lane];
        if (BN) {
            v0 = fmaxf(fmaf(v0, scale, shift), 0.0f);
            v1 = fmaxf(fmaf(v1, scale, shift), 0.0f);
            v2 = fmaxf(fmaf(v2, scale, shift), 0.0f);
            v3 = fmaxf(fmaf(v3, scale, shift), 0.0f);
        }
        sum += (v0 + v1) + (v2 + v3);
    }
    for (; j < d; ++j) {
        float v = x[esrc[s + j] * 64 + lane];
        if (BN) v = fmaxf(fmaf(v, scale, shift), 0.0f);
        sum += v;
    }
    agg[n * 64 + lane] = sum;
}

// ---------------------------------------------------------------------------
// MFMA GIN MLP. Block = 4 waves; wave handles 16 nodes x all 64 output dims.
// h = (1+eps)*bn(x) + agg (agg read from h2buf, h2 written back in place).
// Each GEMM (K=64): split fp32 into bf16 hi/lo, 3 MFMA products per
// (kstep, ntile): Ahi*Bhi + Alo*Bhi + Ahi*Blo  (error ~2^-18, fp32-grade).
// A-frag (16x16x32): A[m=lane&15][k=(lane>>4)*8+j]; C/D: col=lane&15,
// row=(lane>>4)*4+reg  [verified layouts, learn_hip m89/m120].
// h1 goes C-layout -> LDS -> A-layout for GEMM2. BN sums block-reduced in LDS.
// ---------------------------------------------------------------------------
template <bool BN>
__global__ __launch_bounds__(256) void mlp_mfma_kernel(
    const float* __restrict__ x, const float* __restrict__ sc,
    float* __restrict__ h2buf,
    const __bf16* __restrict__ wf1, const __bf16* __restrict__ wf2,
    const float* __restrict__ b1, const float* __restrict__ b2,
    const float* __restrict__ eps_all, int layer,
    float* __restrict__ sums)
{
    __shared__ __attribute__((aligned(16))) unsigned h1p[4][16][68];
    __shared__ float bnacc[128];

    const int tid = threadIdx.x;
    const int lane = tid & 63;
    const int wv = tid >> 6;
    const int q = lane >> 4;      // quad
    const int r = lane & 15;      // row-in-quad / col
    const int node0 = blockIdx.x * 64 + wv * 16;
    const bool active = node0 < N_NODES;

    if (tid < 128) bnacc[tid] = 0.0f;

    f32x4 acc[4];
    float bs[4], bq[4];
#pragma unroll
    for (int nt = 0; nt < 4; ++nt) {
        acc[nt] = (f32x4){0.f, 0.f, 0.f, 0.f};
        bs[nt] = 0.0f; bq[nt] = 0.0f;
    }

    if (active) {
        const float epsv = 1.0f + eps_all[layer];
        // ---- GEMM1: A from global (x + agg), B-frags from weight blob ----
#pragma unroll
        for (int kstep = 0; kstep < 2; ++kstep) {
            const int koff = kstep * 32 + q * 8;
            const float* xr = x + (size_t)(node0 + r) * 64 + koff;
            const float* ar = h2buf + (size_t)(node0 + r) * 64 + koff;
            float4 xa = *(const float4*)xr;
            float4 xb = *(const float4*)(xr + 4);
            float4 aa = *(const float4*)ar;
            float4 ab = *(const float4*)(ar + 4);
            float hv[8];
            const float* xap = (const float*)&xa;
            const float* xbp = (const float*)&xb;
            const float* aap = (const float*)&aa;
            const float* abp = (const float*)&ab;
            if (BN) {
                float4 s0 = *(const float4*)(sc + koff);
                float4 s1 = *(const float4*)(sc + koff + 4);
                float4 t0 = *(const float4*)(sc + 64 + koff);
                float4 t1 = *(const float4*)(sc + 64 + koff + 4);
                const float* s0p = (const float*)&s0;
                const float* s1p = (const float*)&s1;
                const float* t0p = (const float*)&t0;
                const float* t1p = (const float*)&t1;
#pragma unroll
                for (int j = 0; j < 4; ++j) {
                    float xv = fmaxf(fmaf(xap[j], s0p[j], t0p[j]), 0.0f);
                    hv[j] = fmaf(epsv, xv, aap[j]);
                    float xw = fmaxf(fmaf(xbp[j], s1p[j], t1p[j]), 0.0f);
                    hv[4 + j] = fmaf(epsv, xw, abp[j]);
                }
            } else {
#pragma unroll
                for (int j = 0; j < 4; ++j) {
                    hv[j] = fmaf(epsv, xap[j], aap[j]);
                    hv[4 + j] = fmaf(epsv, xbp[j], abp[j]);
                }
            }
            bf16x8 ahi, alo;
#pragma unroll
            for (int j = 0; j < 8; ++j) {
                __bf16 hi = (__bf16)hv[j];
                ahi[j] = hi;
                alo[j] = (__bf16)(hv[j] - (float)hi);
            }
#pragma unroll
            for (int nt = 0; nt < 4; ++nt) {
                const __bf16* bp = wf1 + ((kstep * 4 + nt) * 64 + lane) * 8;
                bf16x8 bhi = *(const bf16x8*)bp;
                bf16x8 blo = *(const bf16x8*)(bp + 4096);
                acc[nt] = __builtin_amdgcn_mfma_f32_16x16x32_bf16(ahi, bhi, acc[nt], 0, 0, 0);
                acc[nt] = __builtin_amdgcn_mfma_f32_16x16x32_bf16(alo, bhi, acc[nt], 0, 0, 0);
                acc[nt] = __builtin_amdgcn_mfma_f32_16x16x32_bf16(ahi, blo, acc[nt], 0, 0, 0);
            }
        }
        // ---- bias + relu, repack h1 (hi|lo) into LDS in A-readable form ----
#pragma unroll
        for (int nt = 0; nt < 4; ++nt) {
            float b1v = b1[nt * 16 + r];
#pragma unroll
            for (int reg = 0; reg < 4; ++reg) {
                float v = fmaxf(acc[nt][reg] + b1v, 0.0f);
                __bf16 hi = (__bf16)v;
                __bf16 lo = (__bf16)(v - (float)hi);
                unsigned pk = ((unsigned)__builtin_bit_cast(unsigned short, hi) << 16)
                            | (unsigned)__builtin_bit_cast(unsigned short, lo);
                h1p[wv][q * 4 + reg][nt * 16 + r] = pk;
            }
            acc[nt] = (f32x4){0.f, 0.f, 0.f, 0.f};
        }
    }
    __syncthreads();
    if (active) {
        // ---- GEMM2: A-frags from LDS ----
#pragma unroll
        for (int kstep = 0; kstep < 2; ++kstep) {
            uint4 p0 = *(const uint4*)&h1p[wv][r][kstep * 32 + q * 8];
            uint4 p1 = *(const uint4*)&h1p[wv][r][kstep * 32 + q * 8 + 4];
            unsigned pk[8] = {p0.x, p0.y, p0.z, p0.w, p1.x, p1.y, p1.z, p1.w};
            bf16x8 ahi, alo;
#pragma unroll
            for (int j = 0; j < 8; ++j) {
                ahi[j] = __builtin_bit_cast(__bf16, (unsigned short)(pk[j] >> 16));
                alo[j] = __builtin_bit_cast(__bf16, (unsigned short)(pk[j] & 0xffffu));
            }
#pragma unroll
            for (int nt = 0; nt < 4; ++nt) {
                const __bf16* bp = wf2 + ((kstep * 4 + nt) * 64 + lane) * 8;
                bf16x8 bhi = *(const bf16x8*)bp;
                bf16x8 blo = *(const bf16x8*)(bp + 4096);
                acc[nt] = __builtin_amdgcn_mfma_f32_16x16x32_bf16(ahi, bhi, acc[nt], 0, 0, 0);
                acc[nt] = __builtin_amdgcn_mfma_f32_16x16x32_bf16(alo, bhi, acc[nt], 0, 0, 0);
                acc[nt] = __builtin_amdgcn_mfma_f32_16x16x32_bf16(ahi, blo, acc[nt], 0, 0, 0);
            }
        }
        // ---- epilogue: bias + relu, store, BN partials ----
#pragma unroll
        for (int nt = 0; nt < 4; ++nt) {
            float b2v = b2[nt * 16 + r];
#pragma unroll
            for (int reg = 0; reg < 4; ++reg) {
                float v = fmaxf(acc[nt][reg] + b2v, 0.0f);
                h2buf[(size_t)(node0 + q * 4 + reg) * 64 + nt * 16 + r] = v;
                bs[nt] += v;
                bq[nt] = fmaf(v, v, bq[nt]);
            }
        }
    }
    // ---- BN reduction: quads -> wave (shfl), waves -> block (LDS atomics) ----
#pragma unroll
    for (int nt = 0; nt < 4; ++nt) {
        float s = bs[nt];
        s += __shfl_xor(s, 16);
        s += __shfl_xor(s, 32);
        float ss = bq[nt];
        ss += __shfl_xor(ss, 16);
        ss += __shfl_xor(ss, 32);
        if (q == 0) {
            atomicAdd(&bnacc[nt * 16 + r], s);
            atomicAdd(&bnacc[64 + nt * 16 + r], ss);
        }
    }
    __syncthreads();
    if (tid < 128) unsafeAtomicAdd(&sums[tid], bnacc[tid]);
}

// ---------------------------------------------------------------------------
// Segmented global mean pool. batch is SORTED: each wave takes a contiguous
// node chunk (lane = dim), register-accumulates per graph, one atomic flush
// per graph-boundary crossing. Applies last layer's BN affine+relu on load.
// ---------------------------------------------------------------------------
__global__ __launch_bounds__(256) void pool_kernel(
    const float* __restrict__ h2, const float* __restrict__ sc,
    const int* __restrict__ batch,
    float* __restrict__ pooled, float* __restrict__ counts)
{
    const int lane = threadIdx.x & 63;
    const int w = blockIdx.x * 4 + (threadIdx.x >> 6);
    const int nw = POOL_BLOCKS * 4;
    const int npw = (N_NODES + nw - 1) / nw;
    int n0 = w * npw;
    if (n0 >= N_NODES) return;
    int n1 = n0 + npw;
    if (n1 > N_NODES) n1 = N_NODES;

    const float scale = sc[lane];
    const float shift = sc[64 + lane];

    int cur = batch[n0];
    float acc = 0.0f, cnt = 0.0f;
    for (int n = n0; n < n1; ++n) {
        int g = batch[n];                       // wave-uniform
        if (g != cur) {                         // wave-uniform branch
            unsafeAtomicAdd(&pooled[cur * 64 + lane], acc);
            if (lane == 0) unsafeAtomicAdd(&counts[cur], cnt);
            acc = 0.0f; cnt = 0.0f; cur = g;
        }
        float v = h2[n * 64 + lane];
        v = fmaxf(fmaf(v, scale, shift), 0.0f);
        acc += v;
        cnt += 1.0f;
    }
    unsafeAtomicAdd(&pooled[cur * 64 + lane], acc);
    if (lane == 0) unsafeAtomicAdd(&counts[cur], cnt);
}

// ---------------------------------------------------------------------------
// Final linear: out[g][o] = (sum_d pooled[g][d]*lin_w[d][o]) / max(cnt,1) + b[o]
// ---------------------------------------------------------------------------
__global__ __launch_bounds__(256) void final_kernel(
    const float* __restrict__ pooled, const float* __restrict__ counts,
    const float* __restrict__ lin_w, const float* __restrict__ lin_b,
    float* __restrict__ out)
{
    int t = blockIdx.x * 256 + threadIdx.x;
    if (t >= N_GRAPHS * OUT_DIM) return;
    int g = t / OUT_DIM;
    int o = t - g * OUT_DIM;
    float acc = 0.0f;
#pragma unroll 8
    for (int d = 0; d < 64; ++d)
        acc = fmaf(pooled[g * 64 + d], lin_w[d * OUT_DIM + o], acc);
    float c = fmaxf(counts[g], 1.0f);
    out[t] = acc / c + lin_b[o];
}

extern "C" void kernel_launch(void* const* d_in, const int* in_sizes, int n_in,
                              void* d_out, int out_size, void* d_ws, size_t ws_size,
                              hipStream_t stream)
{
    const float* x0    = (const float*)d_in[0];
    const int*   ei    = (const int*)d_in[1];
    const int*   batch = (const int*)d_in[2];
    const float* w1    = (const float*)d_in[3];
    const float* b1    = (const float*)d_in[4];
    const float* w2    = (const float*)d_in[5];
    const float* b2    = (const float*)d_in[6];
    const float* gamma = (const float*)d_in[7];
    const float* beta  = (const float*)d_in[8];
    const float* eps_g = (const float*)d_in[9];
    const float* lin_w = (const float*)d_in[10];
    const float* lin_b = (const float*)d_in[11];
    float* out = (float*)d_out;

    // Workspace layout.
    float* ws   = (float*)d_ws;
    float* A    = ws;                                // ping, 6.4M floats
    float* B    = ws + (size_t)N_NODES * 64;         // pong, 6.4M floats
    float* SUMS = ws + (size_t)2 * N_NODES * 64;     // 128
    float* SC   = SUMS + 128;                        // 3 * 128 (scale|shift)
    float* POOL = SC + 3 * 128;                      // 16384
    float* CNT  = POOL + N_GRAPHS * 64;              // 256
    int*   ibase  = (int*)(CNT + N_GRAPHS);
    int*   DEG    = ibase;                            // 100000
    int*   START  = ibase + N_NODES;                  // 100000
    int*   CURSOR = ibase + 2 * N_NODES;              // 100000
    int*   BSUM   = ibase + 3 * N_NODES;              // 512
    int*   ESRC   = ibase + 3 * N_NODES + 512;        // 1000000
    __bf16* WF    = (__bf16*)(ESRC + N_EDGES);        // 6*8192 bf16 = 96 KB

    const int edge_blocks = (N_EDGES + 255) / 256;    // 3907
    const int node_wave_blocks = (N_NODES + 3) / 4;   // 25000

    // ---- weight fragment prep + CSR build (once per call) ----
    wprep_kernel<<<6, 256, 0, stream>>>(w1, w2, WF);
    hipMemsetAsync(DEG, 0, N_NODES * sizeof(int), stream);
    hist_kernel<<<edge_blocks, 256, 0, stream>>>(ei, DEG);
    block_sum_kernel<<<SCAN_NBLK, 256, 0, stream>>>(DEG, BSUM);
    scan_partials_kernel<<<1, 512, 0, stream>>>(BSUM);
    scan_final_kernel<<<SCAN_NBLK, 256, 0, stream>>>(DEG, BSUM, START, CURSOR);
    bucket_kernel<<<edge_blocks, 256, 0, stream>>>(ei, CURSOR, ESRC);

    // ---- 3 GIN layers (BN of layer L fused into consumers of layer L+1) ----
    // L0: x0 -> agg in A -> h2_0 in A
    hipMemsetAsync(SUMS, 0, 128 * sizeof(float), stream);
    gather_kernel<false><<<node_wave_blocks, 256, 0, stream>>>(
        x0, nullptr, START, DEG, ESRC, A);
    mlp_mfma_kernel<false><<<MLP_BLOCKS, 256, 0, stream>>>(
        x0, nullptr, A, WF, WF + 8192, b1, b2, eps_g, 0, SUMS);
    bnprep_kernel<<<1, 64, 0, stream>>>(SUMS, gamma, beta, SC);

    // L1: bn(A) -> agg in B -> h2_1 in B
    hipMemsetAsync(SUMS, 0, 128 * sizeof(float), stream);
    gather_kernel<true><<<node_wave_blocks, 256, 0, stream>>>(
        A, SC, START, DEG, ESRC, B);
    mlp_mfma_kernel<true><<<MLP_BLOCKS, 256, 0, stream>>>(
        A, SC, B, WF + 16384, WF + 24576, b1 + 64, b2 + 64, eps_g, 1, SUMS);
    bnprep_kernel<<<1, 64, 0, stream>>>(SUMS, gamma + 64, beta + 64, SC + 128);

    // L2: bn(B) -> agg in A -> h2_2 in A
    hipMemsetAsync(SUMS, 0, 128 * sizeof(float), stream);
    gather_kernel<true><<<node_wave_blocks, 256, 0, stream>>>(
        B, SC + 128, START, DEG, ESRC, A);
    mlp_mfma_kernel<true><<<MLP_BLOCKS, 256, 0, stream>>>(
        B, SC + 128, A, WF + 32768, WF + 40960, b1 + 128, b2 + 128, eps_g, 2, SUMS);
    bnprep_kernel<<<1, 64, 0, stream>>>(SUMS, gamma + 128, beta + 128, SC + 256);

    // ---- segmented pool (applies bn of L2) + linear ----
    hipMemsetAsync(POOL, 0, (N_GRAPHS * 64 + N_GRAPHS) * sizeof(float), stream);
    pool_kernel<<<POOL_BLOCKS, 256, 0, stream>>>(A, SC + 256, batch, POOL, CNT);
    final_kernel<<<(N_GRAPHS * OUT_DIM + 255) / 256, 256, 0, stream>>>(
        POOL, CNT, lin_w, lin_b, out);
}